// Round 13
// baseline (2002.980 us; speedup 1.0000x reference)
//
#include <hip/hip_runtime.h>
#include <math.h>

// Problem constants (B=8, T=256 -> 2048 independent (b,t) pipelines)
// R18: occupancy probe at the exact fit point + two exact barrier cuts.
// Structure uses exactly 96 unified regs (64 arch + 32 acc). Ladder:
//   bound=4 -> cap 128, uses 96, no spill (R17, 630 us)
//   bound=6 -> cap 64 -> spill catastrophe (R10)
//   bound=5 -> cap 102 >= 96: compiler unchanged; outcome decided by the
//              HW allocation granule (fine -> 5 blk/CU, ~-8%; coarse -> no
//              change). Downside ~0, spill gate = WRITE_SIZE.
// Plus (bit-exact): energy-combine fused into argmax (deletes energy[],
// one barrier, one LDS round-trip per branch); dead residual update at
// it==3 skipped (2 barriers).
#define NBT 2048

typedef __attribute__((ext_vector_type(8))) short short8;     // 8 bf16 (4 VGPRs)
typedef __attribute__((ext_vector_type(4))) float floatx4;    // MFMA C/D

struct SM {
  alignas(16) short xhr[8][264];    // rotated bf16-hi copies: xhr[c][i] = hi(xp[c+i])
  alignas(16) short xlr[8][264];    // rotated bf16-lo copies
  alignas(16) unsigned long long hkey[256];  // rank keys pass 1
  alignas(16) unsigned long long hkey2[256]; // rank keys pass 2 (non-first)
  alignas(16) float yres[80];
  alignas(16) float spadr[4][244];  // rotated sim windows: spadr[c][i] = spad[i+c]
  alignas(16) int2  dpair[64];      // compacted (byte-offset idx*640, float-bits)
  alignas(16) float energyP[4][96]; // per-wave (per-ng) energy partials
  float xres[80];
  float yal[80];
  float xele[80];
  float decsrc[80];
  float zb[80];
  unsigned char mp_self[256];
  unsigned char mp_src[256];
  float ext[160];
  unsigned char smask[80];
  int smask_t;
  // cross-wave scratch
  float abv[4];
  int   abi[4];
  int   wcnt[4];
  float nys;
};

// ---- wave-level primitives (64 lanes, butterfly -> all lanes hold result) ----
__device__ __forceinline__ float waveSum(float v){
  #pragma unroll
  for (int off = 32; off > 0; off >>= 1) v += __shfl_xor(v, off, 64);
  return v;
}
__device__ __forceinline__ int waveSumI(int v){
  #pragma unroll
  for (int off = 32; off > 0; off >>= 1) v += __shfl_xor(v, off, 64);
  return v;
}
__device__ __forceinline__ float waveMax(float v){
  #pragma unroll
  for (int off = 32; off > 0; off >>= 1) v = fmaxf(v, __shfl_xor(v, off, 64));
  return v;
}

// block-wide argmax, JAX tie rule (lowest index wins). Max + min-index is
// associative, so any reduction structure yields the unique answer.
__device__ __forceinline__ int blockArgMax(SM& sm, float v, int idx){
  int lane = threadIdx.x & 63, w = threadIdx.x >> 6;
  #pragma unroll
  for (int off = 32; off > 0; off >>= 1){
    float ov = __shfl_xor(v,   off, 64);
    int   oi = __shfl_xor(idx, off, 64);
    if (ov > v || (ov == v && oi < idx)){ v = ov; idx = oi; }
  }
  if (lane == 0){ sm.abv[w] = v; sm.abi[w] = idx; }
  __syncthreads();
  float bv = sm.abv[0]; int bi = sm.abi[0];
  #pragma unroll
  for (int w2 = 1; w2 < 4; w2++){
    float ov = sm.abv[w2]; int oi = sm.abi[w2];
    if (ov > bv || (ov == bv && oi < bi)){ bv = ov; bi = oi; }
  }
  __syncthreads();   // abv/abi free for reuse after this
  return bi;
}

// top-64 membership via rank over u64 integer keys. vsq >= 0 (squares) =>
// IEEE bits monotone => key_i > key_j <=> v_i > v_j || (v_i==v_j && i<j).
// rank = #{key_i > key_j}; selected iff rank < 64. Keys unique by index =>
// exactly 64 selected. Reads are block-uniform -> LDS broadcast. Fixed
// 128-iteration loop; 4 independent accumulators break the addc chain.
__device__ __forceinline__ int rankTop64(const unsigned long long* keys,
                                         unsigned long long mykey){
  int c0 = 0, c1 = 0, c2 = 0, c3 = 0;
  const ulonglong2* q2 = (const ulonglong2*)keys;
  #pragma unroll 4
  for (int i2 = 0; i2 < 128; i2 += 2){
    ulonglong2 oa = q2[i2];
    ulonglong2 ob = q2[i2 + 1];
    c0 += (oa.x > mykey) ? 1 : 0;
    c1 += (oa.y > mykey) ? 1 : 0;
    c2 += (ob.x > mykey) ? 1 : 0;
    c3 += (ob.y > mykey) ? 1 : 0;
  }
  int cnt = (c0 + c1) + (c2 + c3);
  return (cnt < 64) ? 1 : 0;
}
__device__ __forceinline__ unsigned long long rankKey(float vsq, int j){
  return (((unsigned long long)__float_as_uint(vsq)) << 8)
       | (unsigned long long)(255 - j);
}

// Compact the exactly-64 selected (offset,value) pairs into an ascending-index
// LDS list: per-wave ballot + cross-wave popcount prefix. Ascending order =>
// decode accumulation order matches the reference bit-exactly. The stored
// .x is the PRE-SCALED byte offset idx*640 (Wdec rows are 160 floats).
__device__ __forceinline__ void compactSel(SM& sm, int sel, float val,
                                           unsigned long long below){
  int tid = threadIdx.x, lane = tid & 63, w = tid >> 6;
  unsigned long long mq = __ballot(sel != 0);
  if (lane == 0) sm.wcnt[w] = __popcll(mq);
  __syncthreads();
  int base = 0;
  #pragma unroll
  for (int i = 0; i < 4; i++) base += (i < w) ? sm.wcnt[i] : 0;
  if (sel){
    int pos = base + (int)__popcll(mq & below);
    sm.dpair[pos] = make_int2(tid * 640, __float_as_int(val));
  }
  __syncthreads();   // list ready
}

// sim_argmax: cosine sim over 159 shifts of src vs yres; thread t owns shift t.
// Per-shift fmaf chain order identical to legacy (bit-exact sims). spad is
// held as 4 rotated copies so each thread's 4-wide window read is one
// aligned ds_read_b128 (values bit-identical). nys computed by wave 0
// (legacy butterfly) only when doNy != 0 — yres invariant within iteration.
__device__ __forceinline__ int simArgmax(SM& sm, const float* src, float* yal_out, int doNy){
  int tid = threadIdx.x;
  int lane = tid & 63, w = tid >> 6;
  __syncthreads();
  {
    float v = (tid >= 79 && tid < 159) ? src[tid - 79] : 0.f;
    #pragma unroll
    for (int c = 0; c < 4; c++){
      int i = tid - c;
      if (i >= 0 && i < 240){ sm.spadr[c][i] = v; }
    }
  }
  if (doNy && w == 0){
    float yv2 = 0.f;
    for (int i = lane; i < 80; i += 64){ float yv = sm.yres[i]; yv2 = fmaf(yv, yv, yv2); }
    float ny = sqrtf(waveSum(yv2));
    if (lane == 0) sm.nys = ny;
  }
  __syncthreads();
  float nys = sm.nys;
  float bv = -INFINITY; int bi = 0;
  if (tid < 159){
    const int c = tid & 3;
    const float4* xr = (const float4*)&sm.spadr[c][tid - c];  // 16B aligned
    const float4* y4p = (const float4*)sm.yres;
    float num = 0.f, nx = 0.f;
    for (int w4 = 0; w4 < 20; w4++){
      float4 yy = y4p[w4];
      float4 xa = xr[w4];          // = spad[tid+4w4 .. +3], bit-identical
      num = fmaf(xa.x, yy.x, num); nx = fmaf(xa.x, xa.x, nx);
      num = fmaf(xa.y, yy.y, num); nx = fmaf(xa.y, xa.y, nx);
      num = fmaf(xa.z, yy.z, num); nx = fmaf(xa.z, xa.z, nx);
      num = fmaf(xa.w, yy.w, num); nx = fmaf(xa.w, xa.w, nx);
    }
    bv = num / (sqrtf(nx) * nys + 1e-6f);
    bi = tid;
  }
  int th = blockArgMax(sm, bv, bi);
  if (tid < 80) yal_out[tid] = sm.spadr[0][th + tid];
  __syncthreads();
  return th;
}

// One branch: MFMA energy (split bf16, kt-trimmed — bit-safe; wave w owns
// n-group w, partials summed in legacy ng order; A-frags read as single
// aligned b128 from rotated copies; B-frags streamed per n-tile), fused
// partial-combine + argmax, exact fp32 row recompute (1 j/thread, reads
// enc_in directly), hsr (u64-key dual-array rank), sparse decode
// (1 d/thread), masked loss.
template<int USE_WS>
__device__ __forceinline__ void branchCompute(
    SM& sm, const float* __restrict__ We,
    const short8* __restrict__ wsB,
    const float* __restrict__ Wdec, const float* __restrict__ bdec,
    const float* enc_in, unsigned char* mask, const float* target,
    float* dec_out, int theta, bool first, float& lossAcc,
    float bias_j, const float bn[4], unsigned long long below)
{
  int tid = threadIdx.x;
  int lane = tid & 63, w = tid >> 6;
  int quad = lane >> 4, l15 = lane & 15;
  __syncthreads();
  {
    float v = (tid >= 80 && tid < 160) ? enc_in[tid - 80] : 0.f;
    unsigned bits = __float_as_uint(v);
    unsigned hi = bits >> 16;
    float hif = __uint_as_float(hi << 16);
    unsigned lo = __float_as_uint(v - hif) >> 16;
    short hs = (short)hi, ls = (short)lo;
    // rotated copies: xhr[c][i] = hi(xp[c+i]); A-frag base ≡ l15 (mod 8)
    // -> each fragment is one aligned 16B read. Values bit-identical.
    #pragma unroll
    for (int c = 0; c < 8; c++){
      int i = tid - c;
      if (i >= 0){ sm.xhr[c][i] = hs; sm.xlr[c][i] = ls; }
    }
  }
  __syncthreads();

  const floatx4 zero4 = {0.f, 0.f, 0.f, 0.f};
  const int ng = w;                  // wave w owns n-group w (4 n-tiles)
  const int c8 = l15 & 7;
  const int hb = l15 >> 3;

  #pragma unroll 1
  for (int mh = 0; mh < 3; mh++){    // 2 m-tiles per pass (acc = 32 regs)
    int ktlo = (mh == 0) ? 1 : 0;    // nonzero-support kt range for these m rows
    int kthi = 5 - mh;               // (skipped products are exactly 0 -> bit-safe)
    floatx4 acc[2][4];
    #pragma unroll
    for (int m2 = 0; m2 < 2; m2++)
      #pragma unroll
      for (int nt = 0; nt < 4; nt++) acc[m2][nt] = zero4;

    #pragma unroll 1
    for (int kt = ktlo; kt < kthi; kt++){
      // A fragments for this kt, both m-tiles: single aligned b128 each.
      // base = mt*16 + l15 + kt*32 + quad*8 = (l15&7) + 8*kb
      short8 Ah[2], Al[2];
      #pragma unroll
      for (int m2 = 0; m2 < 2; m2++){
        int mt = mh * 2 + m2;
        int kb = quad + 2 * mt + 4 * kt + hb;
        Ah[m2] = *reinterpret_cast<const short8*>(&sm.xhr[c8][8 * kb]);
        Al[m2] = *reinterpret_cast<const short8*>(&sm.xlr[c8][8 * kb]);
      }
      // stream B per n-tile: only one (Bh,Bl) pair live at a time (x2 unroll)
      #pragma unroll 2
      for (int nt = 0; nt < 4; nt++){
        short8 Bh, Bl;
        int tileIdx = kt * 16 + (ng * 4 + nt);
        if (USE_WS){
          int ti2 = (tileIdx * 64 + lane) * 2;
          Bh = wsB[ti2];
          Bl = wsB[ti2 + 1];
        } else {
          short8 bh, bl;
          int k0 = kt * 32 + quad * 8;
          int n  = (ng * 4 + nt) * 16 + l15;
          #pragma unroll
          for (int j = 0; j < 8; j++){
            float v = We[(k0 + j) * 256 + n];
            unsigned bits = __float_as_uint(v);
            unsigned hi = bits >> 16;
            float hif = __uint_as_float(hi << 16);
            unsigned lo = __float_as_uint(v - hif) >> 16;
            bh[j] = (short)hi; bl[j] = (short)lo;
          }
          Bh = bh; Bl = bl;
        }
        // per-accumulator op order unchanged vs legacy: AhBh, AlBh, AhBl
        acc[0][nt] = __builtin_amdgcn_mfma_f32_16x16x32_bf16(Ah[0], Bh, acc[0][nt], 0, 0, 0);
        acc[0][nt] = __builtin_amdgcn_mfma_f32_16x16x32_bf16(Al[0], Bh, acc[0][nt], 0, 0, 0);
        acc[0][nt] = __builtin_amdgcn_mfma_f32_16x16x32_bf16(Ah[0], Bl, acc[0][nt], 0, 0, 0);
        acc[1][nt] = __builtin_amdgcn_mfma_f32_16x16x32_bf16(Ah[1], Bh, acc[1][nt], 0, 0, 0);
        acc[1][nt] = __builtin_amdgcn_mfma_f32_16x16x32_bf16(Al[1], Bh, acc[1][nt], 0, 0, 0);
        acc[1][nt] = __builtin_amdgcn_mfma_f32_16x16x32_bf16(Ah[1], Bl, acc[1][nt], 0, 0, 0);
      }
    }

    // epilogue: add bias, square, reduce this wave's 64 columns (l15 butterfly,
    // byte-identical to legacy per-ng computation); bn hoisted to registers
    #pragma unroll
    for (int m2 = 0; m2 < 2; m2++){
      int mt = mh * 2 + m2;
      float er[4];
      #pragma unroll
      for (int r = 0; r < 4; r++){
        float s_ = 0.f;
        #pragma unroll
        for (int nt = 0; nt < 4; nt++){
          float hvv = acc[m2][nt][r] + bn[nt];
          s_ = fmaf(hvv, hvv, s_);
        }
        er[r] = s_;
      }
      #pragma unroll
      for (int x2 = 1; x2 < 16; x2 <<= 1){
        #pragma unroll
        for (int r = 0; r < 4; r++) er[r] += __shfl_xor(er[r], x2, 64);
      }
      if (l15 == 0){
        #pragma unroll
        for (int r = 0; r < 4; r++)
          sm.energyP[w][mt * 16 + quad * 4 + r] = er[r];
      }
    }
  }
  __syncthreads();

  // fused combine + argmax over 81 energies: threads < 81 sum the 4 ng
  // partials directly in legacy left-assoc ng order (((ng0+ng1)+ng2)+ng3)
  // -> bit-identical values; padded rows >80 excluded.
  float bvE = -INFINITY; int biE = 0;
  if (tid < 81){
    float e = sm.energyP[0][tid];
    e += sm.energyP[1][tid];
    e += sm.energyP[2][tid];
    e += sm.energyP[3][tid];
    bvE = e; biE = tid;
  }
  int ind = blockArgMax(sm, bvE, biE);

  // recompute selected row h[ind, j] EXACTLY in fp32; thread owns j = tid.
  // enc_in[w2] == legacy xp[80+w2] (pads never read) -> bit-exact chain.
  int roff = 80 - ind;
  float hv = bias_j;
  #pragma unroll 8
  for (int w2 = 0; w2 < 80; w2++){
    float xv = enc_in[w2];
    hv = fmaf(xv, We[(w2 + roff) * 256 + tid], hv);
  }

  // hsr (thread's single j) — u64-key rank, bit-exact selection
  float vsq = hv * hv;
  unsigned long long myk = rankKey(vsq, tid);
  unsigned char mpv = mask[tid];
  if (first){
    sm.hkey[tid] = myk;
    __syncthreads();
    int sel1 = rankTop64(sm.hkey, myk);
    mask[tid] = (unsigned char)sel1;
    compactSel(sm, sel1, hv, below);
  } else {
    // h2 depends only on mpv (known now) -> write BOTH key arrays, 1 barrier
    float h2 = (mpv > 0) ? 0.f : hv;
    unsigned long long myk2 = rankKey(h2 * h2, tid);
    sm.hkey[tid]  = myk;
    sm.hkey2[tid] = myk2;
    __syncthreads();
    int sel1 = rankTop64(sm.hkey,  myk);
    int sel2 = rankTop64(sm.hkey2, myk2);
    int st = sm.smask_t;
    float interv = (float)mpv * (float)sel1;
    if (interv > 0.f && !st){
      float dd = hv - (1.f - interv);
      lossAcc += dd * dd;
    }
    mask[tid] = (unsigned char)(mpv + (unsigned char)sel2);
    compactSel(sm, sel2, h2, below);
  }
  // compactSel ends with a barrier -> dpair ready

  // sparse decode over the exactly-64 selected rows (ascending idx => bit-exact):
  // ext[d] = bdec[d] + sum_{sel h asc} val_h * Wdec[h*160+d]; thread owns d = tid.
  // dpair.x is the pre-scaled byte offset h*640; base pointer hoisted.
  if (tid < 160){
    const char* wbase = (const char*)Wdec + (size_t)(tid * 4);
    float a = bdec[tid];
    #pragma unroll 8
    for (int i = 0; i < 64; i++){
      int2 p = sm.dpair[i];        // block-uniform broadcast, one b64 read
      a = fmaf(__int_as_float(p.y), *(const float*)(wbase + p.x), a);
    }
    sm.ext[tid] = a;
  }
  __syncthreads();

  float mv = fabsf((float)(theta - 79));
  bool gate = (mv > 40.0f);        // ETH
  if (tid < 80){
    float dec = sm.ext[ind + tid];
    dec_out[tid] = dec;            // residual update uses decoded output regardless of gates
    float diff = dec - target[tid];
    float l = (gate || sm.smask[tid]) ? 0.f : diff * diff;
    lossAcc += l / (mv + 1.0f);
  }
  __syncthreads();
}

__global__ void __launch_bounds__(64) zero_out_kernel(float* out){
  if (threadIdx.x == 0) out[0] = 0.f;
}

// Pre-repack We into MFMA B-fragment layout (bf16 hi and lo, interleaved):
// wsB[(tile*64+lane)*2 + {0,1}] = {hi, lo} fragment (16B each).
__global__ void __launch_bounds__(64) prep_we_kernel(
    const float* __restrict__ We, short8* __restrict__ wsB){
  int tile = blockIdx.x;
  int lane = threadIdx.x;
  int kt = tile >> 4, nt = tile & 15;
  int k0 = kt * 32 + (lane >> 4) * 8;
  int n  = nt * 16 + (lane & 15);
  short8 h, l;
  #pragma unroll
  for (int j = 0; j < 8; j++){
    float v = We[(k0 + j) * 256 + n];
    unsigned bits = __float_as_uint(v);
    unsigned hi = bits >> 16;
    float hif = __uint_as_float(hi << 16);
    unsigned lo = __float_as_uint(v - hif) >> 16;
    h[j] = (short)hi; l[j] = (short)lo;
  }
  int ti2 = (tile * 64 + lane) * 2;
  wsB[ti2]     = h;
  wsB[ti2 + 1] = l;
}

template<int USE_WS>
__global__ void __launch_bounds__(256, 5) net_kernel(
    const float* __restrict__ x,  const float* __restrict__ y,
    const float* __restrict__ We, const float* __restrict__ be,
    const float* __restrict__ Wd, const float* __restrict__ bd,
    const float* __restrict__ Wds,const float* __restrict__ bds,
    const short8* __restrict__ wsB,
    float* out)
{
  __shared__ SM sm;
  int tid = threadIdx.x;
  int lane = tid & 63, w = tid >> 6;
  int bt  = blockIdx.x;
  const float* xin = x + bt * 80;
  const float* yin = y + bt * 80;

  if (tid < 80){
    sm.xres[tid] = xin[tid];
    float yv = yin[tid];
    sm.yres[tid] = yv;
    sm.smask[tid] = (yv == 0.f) ? 1 : 0;   // seq_mask from ORIGINAL y
  }
  sm.mp_self[tid] = 0;
  sm.mp_src[tid]  = 0;
  // bias hoists: iteration/branch-invariant, from global, once
  const int l15i = lane & 15;
  float bias_j = be[tid];
  float bn[4];
  #pragma unroll
  for (int nt = 0; nt < 4; nt++) bn[nt] = be[(w * 4 + nt) * 16 + l15i];
  const unsigned long long below =
      (lane == 0) ? 0ull : ((~0ull) >> (64 - lane));
  __syncthreads();
  if (w == 0){
    int c = 0;
    for (int i = lane; i < 80; i += 64) c += (int)sm.smask[i];
    int total = waveSumI(c);
    if (lane == 0) sm.smask_t = (total == 80) ? 1 : 0;
  }
  __syncthreads();

  float lossAcc = 0.f;

  for (int it = 0; it < 4; it++){
    bool first = (it == 0);

    // --- align x_res to y_res (computes nys for this iteration) ---
    int th1 = simArgmax(sm, sm.xres, sm.yal, 1);

    // --- attention softmax(y_al * y_res) and z = y_al * attn ---
    // order-sensitive sum: wave 0 runs the byte-identical legacy code
    if (w == 0){
      float p0 = sm.yal[lane] * sm.yres[lane];
      float p1 = (lane < 16) ? sm.yal[64 + lane] * sm.yres[64 + lane] : -INFINITY;
      float mx = waveMax(fmaxf(p0, p1));
      float e0 = expf(p0 - mx);
      float e1 = (lane < 16) ? expf(p1 - mx) : 0.f;
      float ssum = waveSum(e0 + e1);
      sm.zb[lane] = sm.yal[lane] * (e0 / ssum);
      if (lane < 16) sm.zb[64 + lane] = sm.yal[64 + lane] * (e1 / ssum);
    }
    __syncthreads();

    // --- reverse shift: x_ele[d] = z[d + 79 - theta] ---
    if (tid < 80){
      int q = tid + 79 - th1;
      sm.xele[tid] = (q >= 0 && q < 80) ? sm.zb[q] : 0.f;
    }

    // --- self branch ---
    branchCompute<USE_WS>(sm, We, wsB, Wds, bds,
                          sm.xele, sm.mp_self, sm.xres, sm.xele, th1, first,
                          lossAcc, bias_j, bn, below);

    // --- re-align decoded x_ele to y_res (yres unchanged -> reuse nys) ---
    int th2 = simArgmax(sm, sm.xele, sm.yal, 0);

    // --- src branch ---
    branchCompute<USE_WS>(sm, We, wsB, Wd, bd,
                          sm.yal, sm.mp_src, sm.yres, sm.decsrc, th2, first,
                          lossAcc, bias_j, bn, below);

    // --- residual updates (dead after the last iteration -> skipped) ---
    if (it < 3){
      __syncthreads();
      if (tid < 80){
        sm.xres[tid] -= sm.xele[tid];
        sm.yres[tid] -= sm.decsrc[tid];
      }
      __syncthreads();
    }
  }

  // block loss reduction: per-wave butterfly, then fixed-order 4-way sum
  float vsum = waveSum(lossAcc);
  if (lane == 0) sm.abv[w] = vsum;
  __syncthreads();
  if (tid == 0){
    float total = ((sm.abv[0] + sm.abv[1]) + sm.abv[2]) + sm.abv[3];
    atomicAdd(out, total * 0.25f);   // mean over 4 iterations
  }
}

extern "C" void kernel_launch(void* const* d_in, const int* in_sizes, int n_in,
                              void* d_out, int out_size, void* d_ws, size_t ws_size,
                              hipStream_t stream) {
  const float* x   = (const float*)d_in[0];
  const float* y   = (const float*)d_in[1];
  const float* We  = (const float*)d_in[2];
  const float* be  = (const float*)d_in[3];
  const float* Wd  = (const float*)d_in[4];
  const float* bd  = (const float*)d_in[5];
  const float* Wds = (const float*)d_in[6];
  const float* bds = (const float*)d_in[7];
  float* out = (float*)d_out;

  // We-fragment repack buffer: 80 tiles x 64 lanes x {hi,lo} x 16B = 160 KiB
  const size_t fragCount = 80 * 64 * 2;                 // short8 elements
  const size_t fragBytes = fragCount * sizeof(short8);  // 163840 B
  int use_ws = (ws_size >= fragBytes) ? 1 : 0;
  short8* wsB = (short8*)d_ws;

  hipLaunchKernelGGL(zero_out_kernel, dim3(1), dim3(64), 0, stream, out);
  if (use_ws){
    hipLaunchKernelGGL(prep_we_kernel, dim3(80), dim3(64), 0, stream, We, wsB);
    hipLaunchKernelGGL((net_kernel<1>), dim3(NBT), dim3(256), 0, stream,
                       x, y, We, be, Wd, bd, Wds, bds, wsB, out);
  } else {
    hipLaunchKernelGGL((net_kernel<0>), dim3(NBT), dim3(256), 0, stream,
                       x, y, We, be, Wd, bd, Wds, bds, wsB, out);
  }
}

// Round 14
// 627.321 us; speedup vs baseline: 3.1929x; 3.1929x over previous
//
#include <hip/hip_runtime.h>
#include <math.h>

// Problem constants (B=8, T=256 -> 2048 independent (b,t) pipelines)
// R19: revert R18's occupancy probe, keep its two exact cuts.
// OCCUPANCY LADDER — FULLY MEASURED, DO NOT TOUCH THE BOUND AGAIN:
//   bound=3 -> 920 us (under-occupied, latency-bound)
//   bound=4 -> 630 us (96 unified regs fit in 128 cap; NO spill)  <- optimum
//   bound=5 -> 2.00 ms (allocator granule rounds budget below 96 -> spill)
//   bound=6 -> 2.09 ms (cap 64 -> spill)
// Kept from R18 (bit-exact, orthogonal to the bound):
//  - energy-combine fused into argmax: threads<81 sum the 4 ng partials in
//    legacy left-assoc order and feed blockArgMax directly (deletes
//    energy[], one barrier, one LDS round-trip per branch x8).
//  - dead residual update at it==3 skipped (2 barriers).
#define NBT 2048

typedef __attribute__((ext_vector_type(8))) short short8;     // 8 bf16 (4 VGPRs)
typedef __attribute__((ext_vector_type(4))) float floatx4;    // MFMA C/D

struct SM {
  alignas(16) short xhr[8][264];    // rotated bf16-hi copies: xhr[c][i] = hi(xp[c+i])
  alignas(16) short xlr[8][264];    // rotated bf16-lo copies
  alignas(16) unsigned long long hkey[256];  // rank keys pass 1
  alignas(16) unsigned long long hkey2[256]; // rank keys pass 2 (non-first)
  alignas(16) float yres[80];
  alignas(16) float spadr[4][244];  // rotated sim windows: spadr[c][i] = spad[i+c]
  alignas(16) int2  dpair[64];      // compacted (byte-offset idx*640, float-bits)
  alignas(16) float energyP[4][96]; // per-wave (per-ng) energy partials
  float xres[80];
  float yal[80];
  float xele[80];
  float decsrc[80];
  float zb[80];
  unsigned char mp_self[256];
  unsigned char mp_src[256];
  float ext[160];
  unsigned char smask[80];
  int smask_t;
  // cross-wave scratch
  float abv[4];
  int   abi[4];
  int   wcnt[4];
  float nys;
};

// ---- wave-level primitives (64 lanes, butterfly -> all lanes hold result) ----
__device__ __forceinline__ float waveSum(float v){
  #pragma unroll
  for (int off = 32; off > 0; off >>= 1) v += __shfl_xor(v, off, 64);
  return v;
}
__device__ __forceinline__ int waveSumI(int v){
  #pragma unroll
  for (int off = 32; off > 0; off >>= 1) v += __shfl_xor(v, off, 64);
  return v;
}
__device__ __forceinline__ float waveMax(float v){
  #pragma unroll
  for (int off = 32; off > 0; off >>= 1) v = fmaxf(v, __shfl_xor(v, off, 64));
  return v;
}

// block-wide argmax, JAX tie rule (lowest index wins). Max + min-index is
// associative, so any reduction structure yields the unique answer.
__device__ __forceinline__ int blockArgMax(SM& sm, float v, int idx){
  int lane = threadIdx.x & 63, w = threadIdx.x >> 6;
  #pragma unroll
  for (int off = 32; off > 0; off >>= 1){
    float ov = __shfl_xor(v,   off, 64);
    int   oi = __shfl_xor(idx, off, 64);
    if (ov > v || (ov == v && oi < idx)){ v = ov; idx = oi; }
  }
  if (lane == 0){ sm.abv[w] = v; sm.abi[w] = idx; }
  __syncthreads();
  float bv = sm.abv[0]; int bi = sm.abi[0];
  #pragma unroll
  for (int w2 = 1; w2 < 4; w2++){
    float ov = sm.abv[w2]; int oi = sm.abi[w2];
    if (ov > bv || (ov == bv && oi < bi)){ bv = ov; bi = oi; }
  }
  __syncthreads();   // abv/abi free for reuse after this
  return bi;
}

// top-64 membership via rank over u64 integer keys. vsq >= 0 (squares) =>
// IEEE bits monotone => key_i > key_j <=> v_i > v_j || (v_i==v_j && i<j).
// rank = #{key_i > key_j}; selected iff rank < 64. Keys unique by index =>
// exactly 64 selected. Reads are block-uniform -> LDS broadcast. Fixed
// 128-iteration loop; 4 independent accumulators break the addc chain.
__device__ __forceinline__ int rankTop64(const unsigned long long* keys,
                                         unsigned long long mykey){
  int c0 = 0, c1 = 0, c2 = 0, c3 = 0;
  const ulonglong2* q2 = (const ulonglong2*)keys;
  #pragma unroll 4
  for (int i2 = 0; i2 < 128; i2 += 2){
    ulonglong2 oa = q2[i2];
    ulonglong2 ob = q2[i2 + 1];
    c0 += (oa.x > mykey) ? 1 : 0;
    c1 += (oa.y > mykey) ? 1 : 0;
    c2 += (ob.x > mykey) ? 1 : 0;
    c3 += (ob.y > mykey) ? 1 : 0;
  }
  int cnt = (c0 + c1) + (c2 + c3);
  return (cnt < 64) ? 1 : 0;
}
__device__ __forceinline__ unsigned long long rankKey(float vsq, int j){
  return (((unsigned long long)__float_as_uint(vsq)) << 8)
       | (unsigned long long)(255 - j);
}

// Compact the exactly-64 selected (offset,value) pairs into an ascending-index
// LDS list: per-wave ballot + cross-wave popcount prefix. Ascending order =>
// decode accumulation order matches the reference bit-exactly. The stored
// .x is the PRE-SCALED byte offset idx*640 (Wdec rows are 160 floats).
__device__ __forceinline__ void compactSel(SM& sm, int sel, float val,
                                           unsigned long long below){
  int tid = threadIdx.x, lane = tid & 63, w = tid >> 6;
  unsigned long long mq = __ballot(sel != 0);
  if (lane == 0) sm.wcnt[w] = __popcll(mq);
  __syncthreads();
  int base = 0;
  #pragma unroll
  for (int i = 0; i < 4; i++) base += (i < w) ? sm.wcnt[i] : 0;
  if (sel){
    int pos = base + (int)__popcll(mq & below);
    sm.dpair[pos] = make_int2(tid * 640, __float_as_int(val));
  }
  __syncthreads();   // list ready
}

// sim_argmax: cosine sim over 159 shifts of src vs yres; thread t owns shift t.
// Per-shift fmaf chain order identical to legacy (bit-exact sims). spad is
// held as 4 rotated copies so each thread's 4-wide window read is one
// aligned ds_read_b128 (values bit-identical). nys computed by wave 0
// (legacy butterfly) only when doNy != 0 — yres invariant within iteration.
__device__ __forceinline__ int simArgmax(SM& sm, const float* src, float* yal_out, int doNy){
  int tid = threadIdx.x;
  int lane = tid & 63, w = tid >> 6;
  __syncthreads();
  {
    float v = (tid >= 79 && tid < 159) ? src[tid - 79] : 0.f;
    #pragma unroll
    for (int c = 0; c < 4; c++){
      int i = tid - c;
      if (i >= 0 && i < 240){ sm.spadr[c][i] = v; }
    }
  }
  if (doNy && w == 0){
    float yv2 = 0.f;
    for (int i = lane; i < 80; i += 64){ float yv = sm.yres[i]; yv2 = fmaf(yv, yv, yv2); }
    float ny = sqrtf(waveSum(yv2));
    if (lane == 0) sm.nys = ny;
  }
  __syncthreads();
  float nys = sm.nys;
  float bv = -INFINITY; int bi = 0;
  if (tid < 159){
    const int c = tid & 3;
    const float4* xr = (const float4*)&sm.spadr[c][tid - c];  // 16B aligned
    const float4* y4p = (const float4*)sm.yres;
    float num = 0.f, nx = 0.f;
    for (int w4 = 0; w4 < 20; w4++){
      float4 yy = y4p[w4];
      float4 xa = xr[w4];          // = spad[tid+4w4 .. +3], bit-identical
      num = fmaf(xa.x, yy.x, num); nx = fmaf(xa.x, xa.x, nx);
      num = fmaf(xa.y, yy.y, num); nx = fmaf(xa.y, xa.y, nx);
      num = fmaf(xa.z, yy.z, num); nx = fmaf(xa.z, xa.z, nx);
      num = fmaf(xa.w, yy.w, num); nx = fmaf(xa.w, xa.w, nx);
    }
    bv = num / (sqrtf(nx) * nys + 1e-6f);
    bi = tid;
  }
  int th = blockArgMax(sm, bv, bi);
  if (tid < 80) yal_out[tid] = sm.spadr[0][th + tid];
  __syncthreads();
  return th;
}

// One branch: MFMA energy (split bf16, kt-trimmed — bit-safe; wave w owns
// n-group w, partials summed in legacy ng order; A-frags read as single
// aligned b128 from rotated copies; B-frags streamed per n-tile), fused
// partial-combine + argmax, exact fp32 row recompute (1 j/thread, reads
// enc_in directly), hsr (u64-key dual-array rank), sparse decode
// (1 d/thread), masked loss.
template<int USE_WS>
__device__ __forceinline__ void branchCompute(
    SM& sm, const float* __restrict__ We,
    const short8* __restrict__ wsB,
    const float* __restrict__ Wdec, const float* __restrict__ bdec,
    const float* enc_in, unsigned char* mask, const float* target,
    float* dec_out, int theta, bool first, float& lossAcc,
    float bias_j, const float bn[4], unsigned long long below)
{
  int tid = threadIdx.x;
  int lane = tid & 63, w = tid >> 6;
  int quad = lane >> 4, l15 = lane & 15;
  __syncthreads();
  {
    float v = (tid >= 80 && tid < 160) ? enc_in[tid - 80] : 0.f;
    unsigned bits = __float_as_uint(v);
    unsigned hi = bits >> 16;
    float hif = __uint_as_float(hi << 16);
    unsigned lo = __float_as_uint(v - hif) >> 16;
    short hs = (short)hi, ls = (short)lo;
    // rotated copies: xhr[c][i] = hi(xp[c+i]); A-frag base ≡ l15 (mod 8)
    // -> each fragment is one aligned 16B read. Values bit-identical.
    #pragma unroll
    for (int c = 0; c < 8; c++){
      int i = tid - c;
      if (i >= 0){ sm.xhr[c][i] = hs; sm.xlr[c][i] = ls; }
    }
  }
  __syncthreads();

  const floatx4 zero4 = {0.f, 0.f, 0.f, 0.f};
  const int ng = w;                  // wave w owns n-group w (4 n-tiles)
  const int c8 = l15 & 7;
  const int hb = l15 >> 3;

  #pragma unroll 1
  for (int mh = 0; mh < 3; mh++){    // 2 m-tiles per pass (acc = 32 regs)
    int ktlo = (mh == 0) ? 1 : 0;    // nonzero-support kt range for these m rows
    int kthi = 5 - mh;               // (skipped products are exactly 0 -> bit-safe)
    floatx4 acc[2][4];
    #pragma unroll
    for (int m2 = 0; m2 < 2; m2++)
      #pragma unroll
      for (int nt = 0; nt < 4; nt++) acc[m2][nt] = zero4;

    #pragma unroll 1
    for (int kt = ktlo; kt < kthi; kt++){
      // A fragments for this kt, both m-tiles: single aligned b128 each.
      // base = mt*16 + l15 + kt*32 + quad*8 = (l15&7) + 8*kb
      short8 Ah[2], Al[2];
      #pragma unroll
      for (int m2 = 0; m2 < 2; m2++){
        int mt = mh * 2 + m2;
        int kb = quad + 2 * mt + 4 * kt + hb;
        Ah[m2] = *reinterpret_cast<const short8*>(&sm.xhr[c8][8 * kb]);
        Al[m2] = *reinterpret_cast<const short8*>(&sm.xlr[c8][8 * kb]);
      }
      // stream B per n-tile: only one (Bh,Bl) pair live at a time (x2 unroll)
      #pragma unroll 2
      for (int nt = 0; nt < 4; nt++){
        short8 Bh, Bl;
        int tileIdx = kt * 16 + (ng * 4 + nt);
        if (USE_WS){
          int ti2 = (tileIdx * 64 + lane) * 2;
          Bh = wsB[ti2];
          Bl = wsB[ti2 + 1];
        } else {
          short8 bh, bl;
          int k0 = kt * 32 + quad * 8;
          int n  = (ng * 4 + nt) * 16 + l15;
          #pragma unroll
          for (int j = 0; j < 8; j++){
            float v = We[(k0 + j) * 256 + n];
            unsigned bits = __float_as_uint(v);
            unsigned hi = bits >> 16;
            float hif = __uint_as_float(hi << 16);
            unsigned lo = __float_as_uint(v - hif) >> 16;
            bh[j] = (short)hi; bl[j] = (short)lo;
          }
          Bh = bh; Bl = bl;
        }
        // per-accumulator op order unchanged vs legacy: AhBh, AlBh, AhBl
        acc[0][nt] = __builtin_amdgcn_mfma_f32_16x16x32_bf16(Ah[0], Bh, acc[0][nt], 0, 0, 0);
        acc[0][nt] = __builtin_amdgcn_mfma_f32_16x16x32_bf16(Al[0], Bh, acc[0][nt], 0, 0, 0);
        acc[0][nt] = __builtin_amdgcn_mfma_f32_16x16x32_bf16(Ah[0], Bl, acc[0][nt], 0, 0, 0);
        acc[1][nt] = __builtin_amdgcn_mfma_f32_16x16x32_bf16(Ah[1], Bh, acc[1][nt], 0, 0, 0);
        acc[1][nt] = __builtin_amdgcn_mfma_f32_16x16x32_bf16(Al[1], Bh, acc[1][nt], 0, 0, 0);
        acc[1][nt] = __builtin_amdgcn_mfma_f32_16x16x32_bf16(Ah[1], Bl, acc[1][nt], 0, 0, 0);
      }
    }

    // epilogue: add bias, square, reduce this wave's 64 columns (l15 butterfly,
    // byte-identical to legacy per-ng computation); bn hoisted to registers
    #pragma unroll
    for (int m2 = 0; m2 < 2; m2++){
      int mt = mh * 2 + m2;
      float er[4];
      #pragma unroll
      for (int r = 0; r < 4; r++){
        float s_ = 0.f;
        #pragma unroll
        for (int nt = 0; nt < 4; nt++){
          float hvv = acc[m2][nt][r] + bn[nt];
          s_ = fmaf(hvv, hvv, s_);
        }
        er[r] = s_;
      }
      #pragma unroll
      for (int x2 = 1; x2 < 16; x2 <<= 1){
        #pragma unroll
        for (int r = 0; r < 4; r++) er[r] += __shfl_xor(er[r], x2, 64);
      }
      if (l15 == 0){
        #pragma unroll
        for (int r = 0; r < 4; r++)
          sm.energyP[w][mt * 16 + quad * 4 + r] = er[r];
      }
    }
  }
  __syncthreads();

  // fused combine + argmax over 81 energies: threads < 81 sum the 4 ng
  // partials directly in legacy left-assoc ng order (((ng0+ng1)+ng2)+ng3)
  // -> bit-identical values; padded rows >80 excluded.
  float bvE = -INFINITY; int biE = 0;
  if (tid < 81){
    float e = sm.energyP[0][tid];
    e += sm.energyP[1][tid];
    e += sm.energyP[2][tid];
    e += sm.energyP[3][tid];
    bvE = e; biE = tid;
  }
  int ind = blockArgMax(sm, bvE, biE);

  // recompute selected row h[ind, j] EXACTLY in fp32; thread owns j = tid.
  // enc_in[w2] == legacy xp[80+w2] (pads never read) -> bit-exact chain.
  int roff = 80 - ind;
  float hv = bias_j;
  #pragma unroll 8
  for (int w2 = 0; w2 < 80; w2++){
    float xv = enc_in[w2];
    hv = fmaf(xv, We[(w2 + roff) * 256 + tid], hv);
  }

  // hsr (thread's single j) — u64-key rank, bit-exact selection
  float vsq = hv * hv;
  unsigned long long myk = rankKey(vsq, tid);
  unsigned char mpv = mask[tid];
  if (first){
    sm.hkey[tid] = myk;
    __syncthreads();
    int sel1 = rankTop64(sm.hkey, myk);
    mask[tid] = (unsigned char)sel1;
    compactSel(sm, sel1, hv, below);
  } else {
    // h2 depends only on mpv (known now) -> write BOTH key arrays, 1 barrier
    float h2 = (mpv > 0) ? 0.f : hv;
    unsigned long long myk2 = rankKey(h2 * h2, tid);
    sm.hkey[tid]  = myk;
    sm.hkey2[tid] = myk2;
    __syncthreads();
    int sel1 = rankTop64(sm.hkey,  myk);
    int sel2 = rankTop64(sm.hkey2, myk2);
    int st = sm.smask_t;
    float interv = (float)mpv * (float)sel1;
    if (interv > 0.f && !st){
      float dd = hv - (1.f - interv);
      lossAcc += dd * dd;
    }
    mask[tid] = (unsigned char)(mpv + (unsigned char)sel2);
    compactSel(sm, sel2, h2, below);
  }
  // compactSel ends with a barrier -> dpair ready

  // sparse decode over the exactly-64 selected rows (ascending idx => bit-exact):
  // ext[d] = bdec[d] + sum_{sel h asc} val_h * Wdec[h*160+d]; thread owns d = tid.
  // dpair.x is the pre-scaled byte offset h*640; base pointer hoisted.
  if (tid < 160){
    const char* wbase = (const char*)Wdec + (size_t)(tid * 4);
    float a = bdec[tid];
    #pragma unroll 8
    for (int i = 0; i < 64; i++){
      int2 p = sm.dpair[i];        // block-uniform broadcast, one b64 read
      a = fmaf(__int_as_float(p.y), *(const float*)(wbase + p.x), a);
    }
    sm.ext[tid] = a;
  }
  __syncthreads();

  float mv = fabsf((float)(theta - 79));
  bool gate = (mv > 40.0f);        // ETH
  if (tid < 80){
    float dec = sm.ext[ind + tid];
    dec_out[tid] = dec;            // residual update uses decoded output regardless of gates
    float diff = dec - target[tid];
    float l = (gate || sm.smask[tid]) ? 0.f : diff * diff;
    lossAcc += l / (mv + 1.0f);
  }
  __syncthreads();
}

__global__ void __launch_bounds__(64) zero_out_kernel(float* out){
  if (threadIdx.x == 0) out[0] = 0.f;
}

// Pre-repack We into MFMA B-fragment layout (bf16 hi and lo, interleaved):
// wsB[(tile*64+lane)*2 + {0,1}] = {hi, lo} fragment (16B each).
__global__ void __launch_bounds__(64) prep_we_kernel(
    const float* __restrict__ We, short8* __restrict__ wsB){
  int tile = blockIdx.x;
  int lane = threadIdx.x;
  int kt = tile >> 4, nt = tile & 15;
  int k0 = kt * 32 + (lane >> 4) * 8;
  int n  = nt * 16 + (lane & 15);
  short8 h, l;
  #pragma unroll
  for (int j = 0; j < 8; j++){
    float v = We[(k0 + j) * 256 + n];
    unsigned bits = __float_as_uint(v);
    unsigned hi = bits >> 16;
    float hif = __uint_as_float(hi << 16);
    unsigned lo = __float_as_uint(v - hif) >> 16;
    h[j] = (short)hi; l[j] = (short)lo;
  }
  int ti2 = (tile * 64 + lane) * 2;
  wsB[ti2]     = h;
  wsB[ti2 + 1] = l;
}

template<int USE_WS>
__global__ void __launch_bounds__(256, 4) net_kernel(
    const float* __restrict__ x,  const float* __restrict__ y,
    const float* __restrict__ We, const float* __restrict__ be,
    const float* __restrict__ Wd, const float* __restrict__ bd,
    const float* __restrict__ Wds,const float* __restrict__ bds,
    const short8* __restrict__ wsB,
    float* out)
{
  __shared__ SM sm;
  int tid = threadIdx.x;
  int lane = tid & 63, w = tid >> 6;
  int bt  = blockIdx.x;
  const float* xin = x + bt * 80;
  const float* yin = y + bt * 80;

  if (tid < 80){
    sm.xres[tid] = xin[tid];
    float yv = yin[tid];
    sm.yres[tid] = yv;
    sm.smask[tid] = (yv == 0.f) ? 1 : 0;   // seq_mask from ORIGINAL y
  }
  sm.mp_self[tid] = 0;
  sm.mp_src[tid]  = 0;
  // bias hoists: iteration/branch-invariant, from global, once
  const int l15i = lane & 15;
  float bias_j = be[tid];
  float bn[4];
  #pragma unroll
  for (int nt = 0; nt < 4; nt++) bn[nt] = be[(w * 4 + nt) * 16 + l15i];
  const unsigned long long below =
      (lane == 0) ? 0ull : ((~0ull) >> (64 - lane));
  __syncthreads();
  if (w == 0){
    int c = 0;
    for (int i = lane; i < 80; i += 64) c += (int)sm.smask[i];
    int total = waveSumI(c);
    if (lane == 0) sm.smask_t = (total == 80) ? 1 : 0;
  }
  __syncthreads();

  float lossAcc = 0.f;

  for (int it = 0; it < 4; it++){
    bool first = (it == 0);

    // --- align x_res to y_res (computes nys for this iteration) ---
    int th1 = simArgmax(sm, sm.xres, sm.yal, 1);

    // --- attention softmax(y_al * y_res) and z = y_al * attn ---
    // order-sensitive sum: wave 0 runs the byte-identical legacy code
    if (w == 0){
      float p0 = sm.yal[lane] * sm.yres[lane];
      float p1 = (lane < 16) ? sm.yal[64 + lane] * sm.yres[64 + lane] : -INFINITY;
      float mx = waveMax(fmaxf(p0, p1));
      float e0 = expf(p0 - mx);
      float e1 = (lane < 16) ? expf(p1 - mx) : 0.f;
      float ssum = waveSum(e0 + e1);
      sm.zb[lane] = sm.yal[lane] * (e0 / ssum);
      if (lane < 16) sm.zb[64 + lane] = sm.yal[64 + lane] * (e1 / ssum);
    }
    __syncthreads();

    // --- reverse shift: x_ele[d] = z[d + 79 - theta] ---
    if (tid < 80){
      int q = tid + 79 - th1;
      sm.xele[tid] = (q >= 0 && q < 80) ? sm.zb[q] : 0.f;
    }

    // --- self branch ---
    branchCompute<USE_WS>(sm, We, wsB, Wds, bds,
                          sm.xele, sm.mp_self, sm.xres, sm.xele, th1, first,
                          lossAcc, bias_j, bn, below);

    // --- re-align decoded x_ele to y_res (yres unchanged -> reuse nys) ---
    int th2 = simArgmax(sm, sm.xele, sm.yal, 0);

    // --- src branch ---
    branchCompute<USE_WS>(sm, We, wsB, Wd, bd,
                          sm.yal, sm.mp_src, sm.yres, sm.decsrc, th2, first,
                          lossAcc, bias_j, bn, below);

    // --- residual updates (dead after the last iteration -> skipped) ---
    if (it < 3){
      __syncthreads();
      if (tid < 80){
        sm.xres[tid] -= sm.xele[tid];
        sm.yres[tid] -= sm.decsrc[tid];
      }
      __syncthreads();
    }
  }

  // block loss reduction: per-wave butterfly, then fixed-order 4-way sum
  float vsum = waveSum(lossAcc);
  if (lane == 0) sm.abv[w] = vsum;
  __syncthreads();
  if (tid == 0){
    float total = ((sm.abv[0] + sm.abv[1]) + sm.abv[2]) + sm.abv[3];
    atomicAdd(out, total * 0.25f);   // mean over 4 iterations
  }
}

extern "C" void kernel_launch(void* const* d_in, const int* in_sizes, int n_in,
                              void* d_out, int out_size, void* d_ws, size_t ws_size,
                              hipStream_t stream) {
  const float* x   = (const float*)d_in[0];
  const float* y   = (const float*)d_in[1];
  const float* We  = (const float*)d_in[2];
  const float* be  = (const float*)d_in[3];
  const float* Wd  = (const float*)d_in[4];
  const float* bd  = (const float*)d_in[5];
  const float* Wds = (const float*)d_in[6];
  const float* bds = (const float*)d_in[7];
  float* out = (float*)d_out;

  // We-fragment repack buffer: 80 tiles x 64 lanes x {hi,lo} x 16B = 160 KiB
  const size_t fragCount = 80 * 64 * 2;                 // short8 elements
  const size_t fragBytes = fragCount * sizeof(short8);  // 163840 B
  int use_ws = (ws_size >= fragBytes) ? 1 : 0;
  short8* wsB = (short8*)d_ws;

  hipLaunchKernelGGL(zero_out_kernel, dim3(1), dim3(64), 0, stream, out);
  if (use_ws){
    hipLaunchKernelGGL(prep_we_kernel, dim3(80), dim3(64), 0, stream, We, wsB);
    hipLaunchKernelGGL((net_kernel<1>), dim3(NBT), dim3(256), 0, stream,
                       x, y, We, be, Wd, bd, Wds, bds, wsB, out);
  } else {
    hipLaunchKernelGGL((net_kernel<0>), dim3(NBT), dim3(256), 0, stream,
                       x, y, We, be, Wd, bd, Wds, bds, wsB, out);
  }
}

// Round 15
// 626.117 us; speedup vs baseline: 3.1990x; 1.0019x over previous
//
#include <hip/hip_runtime.h>
#include <math.h>

// Problem constants (B=8, T=256 -> 2048 independent (b,t) pipelines)
// R20: barrier-pruning + validated MFMA trim on the R19 champion (627 us).
// OCCUPANCY LADDER — FULLY MEASURED, DO NOT TOUCH THE BOUND:
//   bound=3: 920us | bound=4: 627us (optimum, no spill) | bound=5/6: spill, ~2ms
// Changes (all bit-exact / ordering-safe):
//  1) blockArgMax trailing barrier removed: every inter-bam path already
//     has >=1 __syncthreads (audited incl. final loss reduction). -16.
//  2) simArgmax entry barrier removed: all call sites immediately follow a
//     barrier (init / branch-final / residual-final). -8.
//  3) branch entry barrier templated: kept for self (reverse-shift writes
//     xele in between), removed for src (sim2 ends with barrier). -4.
//  4) per-mt kt-guard: mh0/kt1 and mh1/kt0 touch only m2=1's support
//     (R14-validated per-mt bounds) -> skip m2=0 A-load + 3 MFMAs there.
//     -24 MFMA/branch. Skipped products are exactly-zero A-tiles.
#define NBT 2048

typedef __attribute__((ext_vector_type(8))) short short8;     // 8 bf16 (4 VGPRs)
typedef __attribute__((ext_vector_type(4))) float floatx4;    // MFMA C/D

struct SM {
  alignas(16) short xhr[8][264];    // rotated bf16-hi copies: xhr[c][i] = hi(xp[c+i])
  alignas(16) short xlr[8][264];    // rotated bf16-lo copies
  alignas(16) unsigned long long hkey[256];  // rank keys pass 1
  alignas(16) unsigned long long hkey2[256]; // rank keys pass 2 (non-first)
  alignas(16) float yres[80];
  alignas(16) float spadr[4][244];  // rotated sim windows: spadr[c][i] = spad[i+c]
  alignas(16) int2  dpair[64];      // compacted (byte-offset idx*640, float-bits)
  alignas(16) float energyP[4][96]; // per-wave (per-ng) energy partials
  float xres[80];
  float yal[80];
  float xele[80];
  float decsrc[80];
  float zb[80];
  unsigned char mp_self[256];
  unsigned char mp_src[256];
  float ext[160];
  unsigned char smask[80];
  int smask_t;
  // cross-wave scratch
  float abv[4];
  int   abi[4];
  int   wcnt[4];
  float nys;
};

// ---- wave-level primitives (64 lanes, butterfly -> all lanes hold result) ----
__device__ __forceinline__ float waveSum(float v){
  #pragma unroll
  for (int off = 32; off > 0; off >>= 1) v += __shfl_xor(v, off, 64);
  return v;
}
__device__ __forceinline__ int waveSumI(int v){
  #pragma unroll
  for (int off = 32; off > 0; off >>= 1) v += __shfl_xor(v, off, 64);
  return v;
}
__device__ __forceinline__ float waveMax(float v){
  #pragma unroll
  for (int off = 32; off > 0; off >>= 1) v = fmaxf(v, __shfl_xor(v, off, 64));
  return v;
}

// block-wide argmax, JAX tie rule (lowest index wins). Max + min-index is
// associative, so any reduction structure yields the unique answer.
// NOTE: no trailing barrier — every path between two bam calls (and to the
// final loss reduction's abv reuse) contains >=1 __syncthreads, so abv/abi
// reads complete before any subsequent write. Audited R20.
__device__ __forceinline__ int blockArgMax(SM& sm, float v, int idx){
  int lane = threadIdx.x & 63, w = threadIdx.x >> 6;
  #pragma unroll
  for (int off = 32; off > 0; off >>= 1){
    float ov = __shfl_xor(v,   off, 64);
    int   oi = __shfl_xor(idx, off, 64);
    if (ov > v || (ov == v && oi < idx)){ v = ov; idx = oi; }
  }
  if (lane == 0){ sm.abv[w] = v; sm.abi[w] = idx; }
  __syncthreads();
  float bv = sm.abv[0]; int bi = sm.abi[0];
  #pragma unroll
  for (int w2 = 1; w2 < 4; w2++){
    float ov = sm.abv[w2]; int oi = sm.abi[w2];
    if (ov > bv || (ov == bv && oi < bi)){ bv = ov; bi = oi; }
  }
  return bi;
}

// top-64 membership via rank over u64 integer keys. vsq >= 0 (squares) =>
// IEEE bits monotone => key_i > key_j <=> v_i > v_j || (v_i==v_j && i<j).
// rank = #{key_i > key_j}; selected iff rank < 64. Keys unique by index =>
// exactly 64 selected. Reads are block-uniform -> LDS broadcast. Fixed
// 128-iteration loop; 4 independent accumulators break the addc chain.
__device__ __forceinline__ int rankTop64(const unsigned long long* keys,
                                         unsigned long long mykey){
  int c0 = 0, c1 = 0, c2 = 0, c3 = 0;
  const ulonglong2* q2 = (const ulonglong2*)keys;
  #pragma unroll 4
  for (int i2 = 0; i2 < 128; i2 += 2){
    ulonglong2 oa = q2[i2];
    ulonglong2 ob = q2[i2 + 1];
    c0 += (oa.x > mykey) ? 1 : 0;
    c1 += (oa.y > mykey) ? 1 : 0;
    c2 += (ob.x > mykey) ? 1 : 0;
    c3 += (ob.y > mykey) ? 1 : 0;
  }
  int cnt = (c0 + c1) + (c2 + c3);
  return (cnt < 64) ? 1 : 0;
}
__device__ __forceinline__ unsigned long long rankKey(float vsq, int j){
  return (((unsigned long long)__float_as_uint(vsq)) << 8)
       | (unsigned long long)(255 - j);
}

// Compact the exactly-64 selected (offset,value) pairs into an ascending-index
// LDS list: per-wave ballot + cross-wave popcount prefix. Ascending order =>
// decode accumulation order matches the reference bit-exactly. The stored
// .x is the PRE-SCALED byte offset idx*640 (Wdec rows are 160 floats).
__device__ __forceinline__ void compactSel(SM& sm, int sel, float val,
                                           unsigned long long below){
  int tid = threadIdx.x, lane = tid & 63, w = tid >> 6;
  unsigned long long mq = __ballot(sel != 0);
  if (lane == 0) sm.wcnt[w] = __popcll(mq);
  __syncthreads();
  int base = 0;
  #pragma unroll
  for (int i = 0; i < 4; i++) base += (i < w) ? sm.wcnt[i] : 0;
  if (sel){
    int pos = base + (int)__popcll(mq & below);
    sm.dpair[pos] = make_int2(tid * 640, __float_as_int(val));
  }
  __syncthreads();   // list ready
}

// sim_argmax: cosine sim over 159 shifts of src vs yres; thread t owns shift t.
// Per-shift fmaf chain order identical to legacy (bit-exact sims). spad is
// held as 4 rotated copies so each thread's 4-wide window read is one
// aligned ds_read_b128 (values bit-identical). nys computed by wave 0
// (legacy butterfly) only when doNy != 0 — yres invariant within iteration.
// NOTE: no entry barrier — every call site immediately follows a barrier.
__device__ __forceinline__ int simArgmax(SM& sm, const float* src, float* yal_out, int doNy){
  int tid = threadIdx.x;
  int lane = tid & 63, w = tid >> 6;
  {
    float v = (tid >= 79 && tid < 159) ? src[tid - 79] : 0.f;
    #pragma unroll
    for (int c = 0; c < 4; c++){
      int i = tid - c;
      if (i >= 0 && i < 240){ sm.spadr[c][i] = v; }
    }
  }
  if (doNy && w == 0){
    float yv2 = 0.f;
    for (int i = lane; i < 80; i += 64){ float yv = sm.yres[i]; yv2 = fmaf(yv, yv, yv2); }
    float ny = sqrtf(waveSum(yv2));
    if (lane == 0) sm.nys = ny;
  }
  __syncthreads();
  float nys = sm.nys;
  float bv = -INFINITY; int bi = 0;
  if (tid < 159){
    const int c = tid & 3;
    const float4* xr = (const float4*)&sm.spadr[c][tid - c];  // 16B aligned
    const float4* y4p = (const float4*)sm.yres;
    float num = 0.f, nx = 0.f;
    for (int w4 = 0; w4 < 20; w4++){
      float4 yy = y4p[w4];
      float4 xa = xr[w4];          // = spad[tid+4w4 .. +3], bit-identical
      num = fmaf(xa.x, yy.x, num); nx = fmaf(xa.x, xa.x, nx);
      num = fmaf(xa.y, yy.y, num); nx = fmaf(xa.y, xa.y, nx);
      num = fmaf(xa.z, yy.z, num); nx = fmaf(xa.z, xa.z, nx);
      num = fmaf(xa.w, yy.w, num); nx = fmaf(xa.w, xa.w, nx);
    }
    bv = num / (sqrtf(nx) * nys + 1e-6f);
    bi = tid;
  }
  int th = blockArgMax(sm, bv, bi);
  if (tid < 80) yal_out[tid] = sm.spadr[0][th + tid];
  __syncthreads();
  return th;
}

// One branch: MFMA energy (split bf16, per-mt kt-trim — bit-safe; wave w
// owns n-group w, partials summed in legacy ng order; A-frags read as
// single aligned b128 from rotated copies; B-frags streamed per n-tile),
// fused partial-combine + argmax, exact fp32 row recompute (1 j/thread,
// reads enc_in directly), hsr (u64-key dual-array rank), sparse decode
// (1 d/thread), masked loss. ENTRY: emit the entry barrier only when the
// caller wrote LDS since its last barrier (self branch's reverse shift).
template<int USE_WS, int ENTRY>
__device__ __forceinline__ void branchCompute(
    SM& sm, const float* __restrict__ We,
    const short8* __restrict__ wsB,
    const float* __restrict__ Wdec, const float* __restrict__ bdec,
    const float* enc_in, unsigned char* mask, const float* target,
    float* dec_out, int theta, bool first, float& lossAcc,
    float bias_j, const float bn[4], unsigned long long below)
{
  int tid = threadIdx.x;
  int lane = tid & 63, w = tid >> 6;
  int quad = lane >> 4, l15 = lane & 15;
  if (ENTRY) __syncthreads();
  {
    float v = (tid >= 80 && tid < 160) ? enc_in[tid - 80] : 0.f;
    unsigned bits = __float_as_uint(v);
    unsigned hi = bits >> 16;
    float hif = __uint_as_float(hi << 16);
    unsigned lo = __float_as_uint(v - hif) >> 16;
    short hs = (short)hi, ls = (short)lo;
    // rotated copies: xhr[c][i] = hi(xp[c+i]); A-frag base ≡ l15 (mod 8)
    // -> each fragment is one aligned 16B read. Values bit-identical.
    #pragma unroll
    for (int c = 0; c < 8; c++){
      int i = tid - c;
      if (i >= 0){ sm.xhr[c][i] = hs; sm.xlr[c][i] = ls; }
    }
  }
  __syncthreads();

  const floatx4 zero4 = {0.f, 0.f, 0.f, 0.f};
  const int ng = w;                  // wave w owns n-group w (4 n-tiles)
  const int c8 = l15 & 7;
  const int hb = l15 >> 3;

  #pragma unroll 1
  for (int mh = 0; mh < 3; mh++){    // 2 m-tiles per pass (acc = 32 regs)
    int ktlo = (mh == 0) ? 1 : 0;    // union nonzero-support kt range
    int kthi = 5 - mh;               // (skipped products are exactly 0 -> bit-safe)
    floatx4 acc[2][4];
    #pragma unroll
    for (int m2 = 0; m2 < 2; m2++)
      #pragma unroll
      for (int nt = 0; nt < 4; nt++) acc[m2][nt] = zero4;

    #pragma unroll 1
    for (int kt = ktlo; kt < kthi; kt++){
      // per-mt trim (R14-validated): m2=0's support excludes mh0/kt1 and
      // mh1/kt0 (those A-tiles are exactly zero) -> skip load + MFMAs.
      const bool do0 = !((mh == 0 && kt == 1) || (mh == 1 && kt == 0));
      // A fragments: single aligned b128 each.
      // base = mt*16 + l15 + kt*32 + quad*8 = (l15&7) + 8*kb
      short8 Ah[2], Al[2];
      {
        int mt = mh * 2 + 1;
        int kb = quad + 2 * mt + 4 * kt + hb;
        Ah[1] = *reinterpret_cast<const short8*>(&sm.xhr[c8][8 * kb]);
        Al[1] = *reinterpret_cast<const short8*>(&sm.xlr[c8][8 * kb]);
      }
      if (do0){
        int mt = mh * 2;
        int kb = quad + 2 * mt + 4 * kt + hb;
        Ah[0] = *reinterpret_cast<const short8*>(&sm.xhr[c8][8 * kb]);
        Al[0] = *reinterpret_cast<const short8*>(&sm.xlr[c8][8 * kb]);
      }
      // stream B per n-tile: only one (Bh,Bl) pair live at a time (x2 unroll)
      #pragma unroll 2
      for (int nt = 0; nt < 4; nt++){
        short8 Bh, Bl;
        int tileIdx = kt * 16 + (ng * 4 + nt);
        if (USE_WS){
          int ti2 = (tileIdx * 64 + lane) * 2;
          Bh = wsB[ti2];
          Bl = wsB[ti2 + 1];
        } else {
          short8 bh, bl;
          int k0 = kt * 32 + quad * 8;
          int n  = (ng * 4 + nt) * 16 + l15;
          #pragma unroll
          for (int j = 0; j < 8; j++){
            float v = We[(k0 + j) * 256 + n];
            unsigned bits = __float_as_uint(v);
            unsigned hi = bits >> 16;
            float hif = __uint_as_float(hi << 16);
            unsigned lo = __float_as_uint(v - hif) >> 16;
            bh[j] = (short)hi; bl[j] = (short)lo;
          }
          Bh = bh; Bl = bl;
        }
        // per-accumulator op order unchanged vs legacy: AhBh, AlBh, AhBl
        if (do0){
          acc[0][nt] = __builtin_amdgcn_mfma_f32_16x16x32_bf16(Ah[0], Bh, acc[0][nt], 0, 0, 0);
          acc[0][nt] = __builtin_amdgcn_mfma_f32_16x16x32_bf16(Al[0], Bh, acc[0][nt], 0, 0, 0);
          acc[0][nt] = __builtin_amdgcn_mfma_f32_16x16x32_bf16(Ah[0], Bl, acc[0][nt], 0, 0, 0);
        }
        acc[1][nt] = __builtin_amdgcn_mfma_f32_16x16x32_bf16(Ah[1], Bh, acc[1][nt], 0, 0, 0);
        acc[1][nt] = __builtin_amdgcn_mfma_f32_16x16x32_bf16(Al[1], Bh, acc[1][nt], 0, 0, 0);
        acc[1][nt] = __builtin_amdgcn_mfma_f32_16x16x32_bf16(Ah[1], Bl, acc[1][nt], 0, 0, 0);
      }
    }

    // epilogue: add bias, square, reduce this wave's 64 columns (l15 butterfly,
    // byte-identical to legacy per-ng computation); bn hoisted to registers
    #pragma unroll
    for (int m2 = 0; m2 < 2; m2++){
      int mt = mh * 2 + m2;
      float er[4];
      #pragma unroll
      for (int r = 0; r < 4; r++){
        float s_ = 0.f;
        #pragma unroll
        for (int nt = 0; nt < 4; nt++){
          float hvv = acc[m2][nt][r] + bn[nt];
          s_ = fmaf(hvv, hvv, s_);
        }
        er[r] = s_;
      }
      #pragma unroll
      for (int x2 = 1; x2 < 16; x2 <<= 1){
        #pragma unroll
        for (int r = 0; r < 4; r++) er[r] += __shfl_xor(er[r], x2, 64);
      }
      if (l15 == 0){
        #pragma unroll
        for (int r = 0; r < 4; r++)
          sm.energyP[w][mt * 16 + quad * 4 + r] = er[r];
      }
    }
  }
  __syncthreads();

  // fused combine + argmax over 81 energies: threads < 81 sum the 4 ng
  // partials directly in legacy left-assoc ng order (((ng0+ng1)+ng2)+ng3)
  // -> bit-identical values; padded rows >80 excluded.
  float bvE = -INFINITY; int biE = 0;
  if (tid < 81){
    float e = sm.energyP[0][tid];
    e += sm.energyP[1][tid];
    e += sm.energyP[2][tid];
    e += sm.energyP[3][tid];
    bvE = e; biE = tid;
  }
  int ind = blockArgMax(sm, bvE, biE);

  // recompute selected row h[ind, j] EXACTLY in fp32; thread owns j = tid.
  // enc_in[w2] == legacy xp[80+w2] (pads never read) -> bit-exact chain.
  int roff = 80 - ind;
  float hv = bias_j;
  #pragma unroll 8
  for (int w2 = 0; w2 < 80; w2++){
    float xv = enc_in[w2];
    hv = fmaf(xv, We[(w2 + roff) * 256 + tid], hv);
  }

  // hsr (thread's single j) — u64-key rank, bit-exact selection
  float vsq = hv * hv;
  unsigned long long myk = rankKey(vsq, tid);
  unsigned char mpv = mask[tid];
  if (first){
    sm.hkey[tid] = myk;
    __syncthreads();
    int sel1 = rankTop64(sm.hkey, myk);
    mask[tid] = (unsigned char)sel1;
    compactSel(sm, sel1, hv, below);
  } else {
    // h2 depends only on mpv (known now) -> write BOTH key arrays, 1 barrier
    float h2 = (mpv > 0) ? 0.f : hv;
    unsigned long long myk2 = rankKey(h2 * h2, tid);
    sm.hkey[tid]  = myk;
    sm.hkey2[tid] = myk2;
    __syncthreads();
    int sel1 = rankTop64(sm.hkey,  myk);
    int sel2 = rankTop64(sm.hkey2, myk2);
    int st = sm.smask_t;
    float interv = (float)mpv * (float)sel1;
    if (interv > 0.f && !st){
      float dd = hv - (1.f - interv);
      lossAcc += dd * dd;
    }
    mask[tid] = (unsigned char)(mpv + (unsigned char)sel2);
    compactSel(sm, sel2, h2, below);
  }
  // compactSel ends with a barrier -> dpair ready

  // sparse decode over the exactly-64 selected rows (ascending idx => bit-exact):
  // ext[d] = bdec[d] + sum_{sel h asc} val_h * Wdec[h*160+d]; thread owns d = tid.
  // dpair.x is the pre-scaled byte offset h*640; base pointer hoisted.
  if (tid < 160){
    const char* wbase = (const char*)Wdec + (size_t)(tid * 4);
    float a = bdec[tid];
    #pragma unroll 8
    for (int i = 0; i < 64; i++){
      int2 p = sm.dpair[i];        // block-uniform broadcast, one b64 read
      a = fmaf(__int_as_float(p.y), *(const float*)(wbase + p.x), a);
    }
    sm.ext[tid] = a;
  }
  __syncthreads();

  float mv = fabsf((float)(theta - 79));
  bool gate = (mv > 40.0f);        // ETH
  if (tid < 80){
    float dec = sm.ext[ind + tid];
    dec_out[tid] = dec;            // residual update uses decoded output regardless of gates
    float diff = dec - target[tid];
    float l = (gate || sm.smask[tid]) ? 0.f : diff * diff;
    lossAcc += l / (mv + 1.0f);
  }
  __syncthreads();
}

__global__ void __launch_bounds__(64) zero_out_kernel(float* out){
  if (threadIdx.x == 0) out[0] = 0.f;
}

// Pre-repack We into MFMA B-fragment layout (bf16 hi and lo, interleaved):
// wsB[(tile*64+lane)*2 + {0,1}] = {hi, lo} fragment (16B each).
__global__ void __launch_bounds__(64) prep_we_kernel(
    const float* __restrict__ We, short8* __restrict__ wsB){
  int tile = blockIdx.x;
  int lane = threadIdx.x;
  int kt = tile >> 4, nt = tile & 15;
  int k0 = kt * 32 + (lane >> 4) * 8;
  int n  = nt * 16 + (lane & 15);
  short8 h, l;
  #pragma unroll
  for (int j = 0; j < 8; j++){
    float v = We[(k0 + j) * 256 + n];
    unsigned bits = __float_as_uint(v);
    unsigned hi = bits >> 16;
    float hif = __uint_as_float(hi << 16);
    unsigned lo = __float_as_uint(v - hif) >> 16;
    h[j] = (short)hi; l[j] = (short)lo;
  }
  int ti2 = (tile * 64 + lane) * 2;
  wsB[ti2]     = h;
  wsB[ti2 + 1] = l;
}

template<int USE_WS>
__global__ void __launch_bounds__(256, 4) net_kernel(
    const float* __restrict__ x,  const float* __restrict__ y,
    const float* __restrict__ We, const float* __restrict__ be,
    const float* __restrict__ Wd, const float* __restrict__ bd,
    const float* __restrict__ Wds,const float* __restrict__ bds,
    const short8* __restrict__ wsB,
    float* out)
{
  __shared__ SM sm;
  int tid = threadIdx.x;
  int lane = tid & 63, w = tid >> 6;
  int bt  = blockIdx.x;
  const float* xin = x + bt * 80;
  const float* yin = y + bt * 80;

  if (tid < 80){
    sm.xres[tid] = xin[tid];
    float yv = yin[tid];
    sm.yres[tid] = yv;
    sm.smask[tid] = (yv == 0.f) ? 1 : 0;   // seq_mask from ORIGINAL y
  }
  sm.mp_self[tid] = 0;
  sm.mp_src[tid]  = 0;
  // bias hoists: iteration/branch-invariant, from global, once
  const int l15i = lane & 15;
  float bias_j = be[tid];
  float bn[4];
  #pragma unroll
  for (int nt = 0; nt < 4; nt++) bn[nt] = be[(w * 4 + nt) * 16 + l15i];
  const unsigned long long below =
      (lane == 0) ? 0ull : ((~0ull) >> (64 - lane));
  __syncthreads();
  if (w == 0){
    int c = 0;
    for (int i = lane; i < 80; i += 64) c += (int)sm.smask[i];
    int total = waveSumI(c);
    if (lane == 0) sm.smask_t = (total == 80) ? 1 : 0;
  }
  __syncthreads();

  float lossAcc = 0.f;

  for (int it = 0; it < 4; it++){
    bool first = (it == 0);

    // --- align x_res to y_res (computes nys for this iteration) ---
    int th1 = simArgmax(sm, sm.xres, sm.yal, 1);

    // --- attention softmax(y_al * y_res) and z = y_al * attn ---
    // order-sensitive sum: wave 0 runs the byte-identical legacy code
    if (w == 0){
      float p0 = sm.yal[lane] * sm.yres[lane];
      float p1 = (lane < 16) ? sm.yal[64 + lane] * sm.yres[64 + lane] : -INFINITY;
      float mx = waveMax(fmaxf(p0, p1));
      float e0 = expf(p0 - mx);
      float e1 = (lane < 16) ? expf(p1 - mx) : 0.f;
      float ssum = waveSum(e0 + e1);
      sm.zb[lane] = sm.yal[lane] * (e0 / ssum);
      if (lane < 16) sm.zb[64 + lane] = sm.yal[64 + lane] * (e1 / ssum);
    }
    __syncthreads();

    // --- reverse shift: x_ele[d] = z[d + 79 - theta] ---
    if (tid < 80){
      int q = tid + 79 - th1;
      sm.xele[tid] = (q >= 0 && q < 80) ? sm.zb[q] : 0.f;
    }

    // --- self branch (ENTRY=1: xele written since last barrier) ---
    branchCompute<USE_WS, 1>(sm, We, wsB, Wds, bds,
                             sm.xele, sm.mp_self, sm.xres, sm.xele, th1, first,
                             lossAcc, bias_j, bn, below);

    // --- re-align decoded x_ele to y_res (yres unchanged -> reuse nys) ---
    int th2 = simArgmax(sm, sm.xele, sm.yal, 0);

    // --- src branch (ENTRY=0: sim2 ended with a barrier, nothing between) ---
    branchCompute<USE_WS, 0>(sm, We, wsB, Wd, bd,
                             sm.yal, sm.mp_src, sm.yres, sm.decsrc, th2, first,
                             lossAcc, bias_j, bn, below);

    // --- residual updates (dead after the last iteration -> skipped) ---
    if (it < 3){
      __syncthreads();
      if (tid < 80){
        sm.xres[tid] -= sm.xele[tid];
        sm.yres[tid] -= sm.decsrc[tid];
      }
      __syncthreads();
    }
  }

  // block loss reduction: per-wave butterfly, then fixed-order 4-way sum
  float vsum = waveSum(lossAcc);
  if (lane == 0) sm.abv[w] = vsum;
  __syncthreads();
  if (tid == 0){
    float total = ((sm.abv[0] + sm.abv[1]) + sm.abv[2]) + sm.abv[3];
    atomicAdd(out, total * 0.25f);   // mean over 4 iterations
  }
}

extern "C" void kernel_launch(void* const* d_in, const int* in_sizes, int n_in,
                              void* d_out, int out_size, void* d_ws, size_t ws_size,
                              hipStream_t stream) {
  const float* x   = (const float*)d_in[0];
  const float* y   = (const float*)d_in[1];
  const float* We  = (const float*)d_in[2];
  const float* be  = (const float*)d_in[3];
  const float* Wd  = (const float*)d_in[4];
  const float* bd  = (const float*)d_in[5];
  const float* Wds = (const float*)d_in[6];
  const float* bds = (const float*)d_in[7];
  float* out = (float*)d_out;

  // We-fragment repack buffer: 80 tiles x 64 lanes x {hi,lo} x 16B = 160 KiB
  const size_t fragCount = 80 * 64 * 2;                 // short8 elements
  const size_t fragBytes = fragCount * sizeof(short8);  // 163840 B
  int use_ws = (ws_size >= fragBytes) ? 1 : 0;
  short8* wsB = (short8*)d_ws;

  hipLaunchKernelGGL(zero_out_kernel, dim3(1), dim3(64), 0, stream, out);
  if (use_ws){
    hipLaunchKernelGGL(prep_we_kernel, dim3(80), dim3(64), 0, stream, We, wsB);
    hipLaunchKernelGGL((net_kernel<1>), dim3(NBT), dim3(256), 0, stream,
                       x, y, We, be, Wd, bd, Wds, bds, wsB, out);
  } else {
    hipLaunchKernelGGL((net_kernel<0>), dim3(NBT), dim3(256), 0, stream,
                       x, y, We, be, Wd, bd, Wds, bds, wsB, out);
  }
}